// Round 1
// baseline (63.290 us; speedup 1.0000x reference)
//
#include <hip/hip_runtime.h>

#define B_SIZE 4096
#define IN_F   8192
#define OUT_W  8194           // IN_F + 2 after slicing off the 2-pads
#define ROWS_PER_BLOCK 16

// ---------------------------------------------------------------------------
// Kernel 1: gather the 3 band diagonals + bias*count into coeff[j] = float4
//   c = j + 2 (output column in the un-sliced frame)
//   coeff[j] = { W[c,j], W[c,j+1], W[c,j+2], count(c)*bias[c] }
//   (entries with n >= IN_F are zeroed; columns 8192/8193 end up all-zero)
// ---------------------------------------------------------------------------
__global__ __launch_bounds__(256) void coeff_kernel(
    const float* __restrict__ w, const float* __restrict__ bias,
    float4* __restrict__ coeff) {
  int j = blockIdx.x * blockDim.x + threadIdx.x;
  if (j >= OUT_W) return;
  size_t c = (size_t)j + 2;
  float c0 = 0.f, c1 = 0.f, c2 = 0.f, cnt = 0.f;
  if (j     < IN_F) { c0 = w[c * IN_F + j    ]; cnt += 1.f; }
  if (j + 1 < IN_F) { c1 = w[c * IN_F + j + 1]; cnt += 1.f; }
  if (j + 2 < IN_F) { c2 = w[c * IN_F + j + 2]; cnt += 1.f; }
  coeff[j] = make_float4(c0, c1, c2, cnt * bias[c]);
}

// ---------------------------------------------------------------------------
// Kernel 2: streaming 3-tap band apply.
//   grid.x = 8 column chunks (each block covers 1024 consecutive columns,
//            thread t owns columns j..j+3, j = (bx*256+t)*4)
//   grid.y = row strips of ROWS_PER_BLOCK rows; coeffs stay in registers
//            across the row loop.
//   out[b][j] = k.x*x[b][j] + k.y*x[b][j+1] + k.z*x[b][j+2] + k.w
//   Stores as 2x float2: row byte stride 32776 is 8B- but not 16B-aligned.
// ---------------------------------------------------------------------------
__global__ __launch_bounds__(256) void band_kernel(
    const float* __restrict__ x, const float4* __restrict__ coeff,
    float* __restrict__ out) {
  const int j = (blockIdx.x * 256 + threadIdx.x) * 4;   // [0, 8192) step 4
  const float4 k0 = coeff[j];
  const float4 k1 = coeff[j + 1];
  const float4 k2 = coeff[j + 2];
  const float4 k3 = coeff[j + 3];
  const bool g4 = (j + 4 < IN_F);          // only false for the last thread
  const bool g5 = (j + 5 < IN_F);
  const bool tail = (blockIdx.x == gridDim.x - 1) && (threadIdx.x < 2);
  const int row0 = blockIdx.y * ROWS_PER_BLOCK;

  #pragma unroll 4
  for (int r = 0; r < ROWS_PER_BLOCK; ++r) {
    const size_t row = (size_t)(row0 + r);
    const float* xr = x + row * (size_t)IN_F;
    float4 xv = *reinterpret_cast<const float4*>(xr + j);   // 16B aligned
    float x4 = g4 ? xr[j + 4] : 0.f;
    float x5 = g5 ? xr[j + 5] : 0.f;
    float4 o;
    o.x = fmaf(k0.x, xv.x, fmaf(k0.y, xv.y, fmaf(k0.z, xv.z, k0.w)));
    o.y = fmaf(k1.x, xv.y, fmaf(k1.y, xv.z, fmaf(k1.z, xv.w, k1.w)));
    o.z = fmaf(k2.x, xv.z, fmaf(k2.y, xv.w, fmaf(k2.z, x4,  k2.w)));
    o.w = fmaf(k3.x, xv.w, fmaf(k3.y, x4,  fmaf(k3.z, x5,  k3.w)));
    float* orow = out + row * (size_t)OUT_W + j;
    reinterpret_cast<float2*>(orow)[0] = make_float2(o.x, o.y);
    reinterpret_cast<float2*>(orow)[1] = make_float2(o.z, o.w);
    // last two output columns are exactly zero (no valid input taps)
    if (tail) out[row * (size_t)OUT_W + 8192 + threadIdx.x] = 0.f;
  }
}

extern "C" void kernel_launch(void* const* d_in, const int* in_sizes, int n_in,
                              void* d_out, int out_size, void* d_ws, size_t ws_size,
                              hipStream_t stream) {
  const float* x    = (const float*)d_in[0];   // [4096, 8192]
  const float* w    = (const float*)d_in[1];   // [8198, 8192]
  const float* bias = (const float*)d_in[2];   // [8198]
  float* out = (float*)d_out;                  // [4096, 8194]
  float4* coeff = (float4*)d_ws;               // 8194 * 16 B = 131 KB scratch

  coeff_kernel<<<(OUT_W + 255) / 256, 256, 0, stream>>>(w, bias, coeff);

  dim3 grid(8, B_SIZE / ROWS_PER_BLOCK);       // 8 col-chunks x 256 row strips
  band_kernel<<<grid, 256, 0, stream>>>(x, coeff, out);
}